// Round 2
// baseline (406.721 us; speedup 1.0000x reference)
//
#include <hip/hip_runtime.h>

#define B_   4
#define NQ_  512
#define NK_  512
#define D_   512
#define H_   128

__device__ __forceinline__ float fexp2(float x) { return __builtin_amdgcn_exp2f(x); }
__device__ __forceinline__ float frcp(float x)  { return __builtin_amdgcn_rcpf(x); }

// ---------------------------------------------------------------------------
// Kernel A: P = X @ W   (X: (2048,512), W: (512,128)), fp32.
// 8 rows x 128 cols per block -> grid (256,1,2) = 512 blocks (2/CU).
// W is read directly from global (256 KB, L2-hot, broadcast-coalesced);
// X staged through a small LDS chunk (8x64).
// ---------------------------------------------------------------------------
__global__ __launch_bounds__(256) void proj_kernel(
    const float* __restrict__ Q, const float* __restrict__ K,
    const float* __restrict__ Wq, const float* __restrict__ Wk,
    float* __restrict__ Qp, float* __restrict__ Kp)
{
    const int z = blockIdx.z;
    const float* __restrict__ X = z ? K  : Q;
    const float* __restrict__ W = z ? Wk : Wq;
    float* __restrict__ P       = z ? Kp : Qp;

    const int r0 = blockIdx.x * 8;
    const int t  = threadIdx.x;
    const int cg  = t & 31;   // col group: cols 4*cg .. 4*cg+3
    const int row = t >> 5;   // 0..7

    __shared__ float Xs[8][68];   // [row][k-chunk], 16B-aligned row stride (68*4=272)

    float4 acc = make_float4(0.f, 0.f, 0.f, 0.f);

    for (int kk = 0; kk < D_; kk += 64) {
        if (t < 128) {
            const int sr = t >> 4;          // 0..7
            const int kq = (t & 15) * 4;    // 0..60
            const float4 v = *reinterpret_cast<const float4*>(
                X + (size_t)(r0 + sr) * D_ + kk + kq);
            *reinterpret_cast<float4*>(&Xs[sr][kq]) = v;
        }
        __syncthreads();

        #pragma unroll
        for (int k4 = 0; k4 < 16; ++k4) {
            const float4 xv = *reinterpret_cast<const float4*>(&Xs[row][k4 * 4]);
            const float xa[4] = {xv.x, xv.y, xv.z, xv.w};
            #pragma unroll
            for (int j = 0; j < 4; ++j) {
                const float4 wv4 = *reinterpret_cast<const float4*>(
                    W + (size_t)(kk + k4 * 4 + j) * H_ + cg * 4);
                acc.x = fmaf(xa[j], wv4.x, acc.x);
                acc.y = fmaf(xa[j], wv4.y, acc.y);
                acc.z = fmaf(xa[j], wv4.z, acc.z);
                acc.w = fmaf(xa[j], wv4.w, acc.w);
            }
        }
        __syncthreads();
    }

    *reinterpret_cast<float4*>(P + (size_t)(r0 + row) * H_ + cg * 4) = acc;
}

// ---------------------------------------------------------------------------
// Kernel B: scores + masked softmax.
// Block: 2 q-rows x 512 k for one batch, 256 threads -> grid (256,4) = 1024
// blocks (4/CU, 16 waves/CU). K-rows streamed per-lane from L2 (64B groups).
//   score'[q,k] = sum_h wn_h / (1 + e^{2(qh+kh)}),  wn = -2*wv
// (additive const sum_h wv cancels in softmax). Reciprocals fused pairwise:
//   wn0/(1+a) + wn1/(1+b) = [s01 + wn0*b + wn1*a] * rcp((1+a)(1+b))
// -> 4 exp2 + 2 rcp per 4 h (was 4+4).
// ---------------------------------------------------------------------------
__global__ __launch_bounds__(256) void score_softmax_kernel(
    const float* __restrict__ Qp, const float* __restrict__ Kp,
    const float* __restrict__ wv, const int* __restrict__ valid_lens,
    float* __restrict__ Wt)
{
    const int b  = blockIdx.y;
    const int q0 = blockIdx.x * 2;
    const int t  = threadIdx.x;

    __shared__ __align__(16) float4 Qs[2][33];  // pre-scaled by 2*log2(e)
    __shared__ __align__(16) float4 wp[64];     // (wn0, wn1, wn0+wn1, 0) per h-pair
    __shared__ __align__(16) float  Sc[2][516];

    const float C2 = 2.88539008177792681472f;   // 2*log2(e)

    if (t < 64) {
        const float2 w2 = reinterpret_cast<const float2*>(wv)[t];
        const float wn0 = -2.0f * w2.x;
        const float wn1 = -2.0f * w2.y;
        wp[t] = make_float4(wn0, wn1, wn0 + wn1, 0.0f);
    } else if (t < 128) {
        const int i  = t - 64;
        const int q  = i >> 5;
        const int h4 = i & 31;
        float4 v = *reinterpret_cast<const float4*>(
            Qp + ((size_t)(b * NQ_ + q0 + q)) * H_ + h4 * 4);
        v.x *= C2; v.y *= C2; v.z *= C2; v.w *= C2;
        Qs[q][h4] = v;
    }
    __syncthreads();

    {
        const int q  = t >> 7;    // 0..1
        const int kl = t & 127;   // 0..127

        #pragma unroll
        for (int kc = 0; kc < 4; ++kc) {
            const int k = kc * 128 + kl;
            const float* __restrict__ krow = Kp + ((size_t)(b * NK_) + k) * H_;
            float s = 0.0f;
            #pragma unroll
            for (int h16 = 0; h16 < 8; ++h16) {
                // one 64B line per lane per group
                const float4 kv0 = *reinterpret_cast<const float4*>(krow + h16 * 16 + 0);
                const float4 kv1 = *reinterpret_cast<const float4*>(krow + h16 * 16 + 4);
                const float4 kv2 = *reinterpret_cast<const float4*>(krow + h16 * 16 + 8);
                const float4 kv3 = *reinterpret_cast<const float4*>(krow + h16 * 16 + 12);
                const float4 kvs[4] = {kv0, kv1, kv2, kv3};
                #pragma unroll
                for (int j = 0; j < 4; ++j) {
                    const int h4 = h16 * 4 + j;
                    const float4 kv = kvs[j];
                    const float4 qv = Qs[q][h4];
                    const float4 wa = wp[h4 * 2 + 0];
                    const float4 wb = wp[h4 * 2 + 1];
                    const float x0 = fmaf(C2, kv.x, qv.x);
                    const float x1 = fmaf(C2, kv.y, qv.y);
                    const float x2 = fmaf(C2, kv.z, qv.z);
                    const float x3 = fmaf(C2, kv.w, qv.w);
                    const float ea = fexp2(x0);
                    const float eb = fexp2(x1);
                    const float ec = fexp2(x2);
                    const float ed = fexp2(x3);
                    float n0 = fmaf(wa.x, eb, wa.z); n0 = fmaf(wa.y, ea, n0);
                    float n1 = fmaf(wb.x, ed, wb.z); n1 = fmaf(wb.y, ec, n1);
                    const float d0 = (1.0f + ea) * (1.0f + eb);
                    const float d1 = (1.0f + ec) * (1.0f + ed);
                    s = fmaf(n0, frcp(d0), s);
                    s = fmaf(n1, frcp(d1), s);
                }
            }
            Sc[q][k] = s;
        }
    }
    __syncthreads();

    // softmax: wave 0 -> row 0, wave 1 -> row 1; waves 2,3 done
    const int wave = t >> 6;
    if (wave < 2) {
        const int lane = t & 63;
        const int row  = wave;
        const int vl   = valid_lens[b];

        float vals[8];
        float m = -1e30f;
        #pragma unroll
        for (int j = 0; j < 8; ++j) {
            const int k = j * 64 + lane;
            float sv = Sc[row][k];
            sv = (k < vl) ? sv : -1e30f;
            vals[j] = sv;
            m = fmaxf(m, sv);
        }
        #pragma unroll
        for (int off = 32; off >= 1; off >>= 1)
            m = fmaxf(m, __shfl_xor(m, off, 64));

        const float L2E = 1.44269504088896340736f;
        float e[8];
        float sum = 0.0f;
        #pragma unroll
        for (int j = 0; j < 8; ++j) {
            e[j] = fexp2((vals[j] - m) * L2E);
            sum += e[j];
        }
        #pragma unroll
        for (int off = 32; off >= 1; off >>= 1)
            sum += __shfl_xor(sum, off, 64);

        const float inv = frcp(sum);
        float* __restrict__ dst = Wt + ((size_t)(b * NQ_ + q0 + row)) * NK_;
        #pragma unroll
        for (int j = 0; j < 8; ++j)
            dst[j * 64 + lane] = e[j] * inv;
    }
}

// ---------------------------------------------------------------------------
// Kernel C: O[b] = Wt[b] @ V[b], fp32, k-split 2.
// grid (8,8,8): z = b*2+half; half 0 -> d_out, half 1 -> partial buffer.
// ---------------------------------------------------------------------------
__global__ __launch_bounds__(256) void av_gemm_kernel(
    const float* __restrict__ Wt, const float* __restrict__ V,
    float* __restrict__ O, float* __restrict__ P1)
{
    const int bz   = blockIdx.z;
    const int b    = bz >> 1;
    const int half = bz & 1;
    const int r0 = blockIdx.y * 64;
    const int c0 = blockIdx.x * 64;
    const int t  = threadIdx.x;
    const int cg = t & 15;
    const int rg = t >> 4;

    __shared__ float At[16][68];
    __shared__ float Bl[16][68];

    const float* __restrict__ Wb = Wt + (size_t)b * NQ_ * NK_;
    const float* __restrict__ Vb = V  + (size_t)b * NK_ * D_;

    float acc[4][4] = {};

    const int k0 = half * 256;
    for (int kk = k0; kk < k0 + 256; kk += 16) {
        {
            const int row = t >> 2;
            const int kq  = (t & 3) * 4;
            const float4 v = *reinterpret_cast<const float4*>(
                Wb + (size_t)(r0 + row) * NK_ + kk + kq);
            At[kq + 0][row] = v.x;
            At[kq + 1][row] = v.y;
            At[kq + 2][row] = v.z;
            At[kq + 3][row] = v.w;
        }
        {
            const int kr = t >> 4;
            const int cq = (t & 15) * 4;
            *reinterpret_cast<float4*>(&Bl[kr][cq]) =
                *reinterpret_cast<const float4*>(
                    Vb + (size_t)(kk + kr) * D_ + c0 + cq);
        }
        __syncthreads();

        #pragma unroll
        for (int k = 0; k < 16; ++k) {
            const float4 av = *reinterpret_cast<const float4*>(&At[k][rg * 4]);
            const float4 bv = *reinterpret_cast<const float4*>(&Bl[k][cg * 4]);
            const float aa[4] = {av.x, av.y, av.z, av.w};
            const float bb[4] = {bv.x, bv.y, bv.z, bv.w};
            #pragma unroll
            for (int r = 0; r < 4; ++r)
                #pragma unroll
                for (int c = 0; c < 4; ++c)
                    acc[r][c] = fmaf(aa[r], bb[c], acc[r][c]);
        }
        __syncthreads();
    }

    float* __restrict__ dst = half ? P1 : O;
    #pragma unroll
    for (int r = 0; r < 4; ++r) {
        float4 v = make_float4(acc[r][0], acc[r][1], acc[r][2], acc[r][3]);
        *reinterpret_cast<float4*>(
            dst + ((size_t)b * NQ_ + r0 + rg * 4 + r) * D_ + c0 + cg * 4) = v;
    }
}

// ---------------------------------------------------------------------------
// Kernel D: O += P1 (float4), 1M floats.
// ---------------------------------------------------------------------------
__global__ __launch_bounds__(256) void add_kernel(
    float4* __restrict__ O, const float4* __restrict__ P1)
{
    const int i = blockIdx.x * 256 + threadIdx.x;
    const float4 a = O[i];
    const float4 p = P1[i];
    O[i] = make_float4(a.x + p.x, a.y + p.y, a.z + p.z, a.w + p.w);
}

extern "C" void kernel_launch(void* const* d_in, const int* in_sizes, int n_in,
                              void* d_out, int out_size, void* d_ws, size_t ws_size,
                              hipStream_t stream) {
    (void)in_sizes; (void)n_in; (void)out_size; (void)ws_size;

    const float* Q   = (const float*)d_in[0];
    const float* K   = (const float*)d_in[1];
    const float* V   = (const float*)d_in[2];
    const float* Wq  = (const float*)d_in[3];
    const float* Wk  = (const float*)d_in[4];
    const float* wv  = (const float*)d_in[5];
    const int*   vl  = (const int*)d_in[6];
    float* out = (float*)d_out;

    float* ws = (float*)d_ws;
    float* Qp = ws;                       // 262144 floats
    float* Kp = ws + 262144;              // 262144 floats
    float* Wt = ws + 524288;              // 1048576 floats
    float* P1 = ws + 1572864;             // 1048576 floats (k-split partial)

    proj_kernel<<<dim3(256, 1, 2), 256, 0, stream>>>(Q, K, Wq, Wk, Qp, Kp);
    score_softmax_kernel<<<dim3(NQ_ / 2, B_), 256, 0, stream>>>(Qp, Kp, wv, vl, Wt);
    av_gemm_kernel<<<dim3(8, 8, 8), 256, 0, stream>>>(Wt, V, out, P1);
    add_kernel<<<dim3(1024), 256, 0, stream>>>((float4*)out, (const float4*)P1);
}

// Round 3
// 144.998 us; speedup vs baseline: 2.8050x; 2.8050x over previous
//
#include <hip/hip_runtime.h>

#define B_   4
#define NQ_  512
#define NK_  512
#define D_   512
#define H_   128

__device__ __forceinline__ float fexp2(float x) { return __builtin_amdgcn_exp2f(x); }
__device__ __forceinline__ float frcp(float x)  { return __builtin_amdgcn_rcpf(x); }

// ws layout (float offsets)
#define WS_QKP   0          // [4096][128]  Qp rows 0..2047, Kp rows 2048..4095 (pre-scaled by 2*log2e)
#define WS_PP    1048576    // [8][4096][128] proj partials
#define WS_WP    5242880    // [64] float4 pair table (wn0, wn1, wn0+wn1, 0)
#define WS_SC    6291456    // [4][512][512] scores -> softmax weights (in place)
#define WS_PG    8388608    // [8][2048][512] gemm partials

// ---------------------------------------------------------------------------
// proj: partial X@W. Row-blocks 0..31 = Q@Wq, 32..63 = K@Wk. k-split 8.
// Block: 64 rows x 128 cols, 256 thr, 4x8 thread tile. grid (64, 8).
// ---------------------------------------------------------------------------
__global__ __launch_bounds__(256) void proj_kernel(
    const float* __restrict__ Q, const float* __restrict__ K,
    const float* __restrict__ Wq, const float* __restrict__ Wk,
    float* __restrict__ Pp)
{
    const int xb = blockIdx.x;          // 0..63
    const int ks = blockIdx.y;          // 0..7
    const bool isQ = xb < 32;
    const float* __restrict__ X = isQ ? Q : Q;  // placeholder, fixed below
    X = isQ ? Q : K;
    const float* __restrict__ W = isQ ? Wq : Wk;
    const int r0 = (xb & 31) * 64;      // row within its matrix
    const int k0 = ks * 64;
    const int t  = threadIdx.x;

    __shared__ float At[64][68];    // [k][row], transposed
    __shared__ float Wl[64][132];   // [k][col]

    #pragma unroll
    for (int p = 0; p < 4; ++p) {
        const int idx = p * 256 + t;        // 0..1023
        const int row = idx >> 4;           // 0..63
        const int kq  = (idx & 15) * 4;
        const float4 v = *reinterpret_cast<const float4*>(
            X + (size_t)(r0 + row) * D_ + k0 + kq);
        At[kq + 0][row] = v.x; At[kq + 1][row] = v.y;
        At[kq + 2][row] = v.z; At[kq + 3][row] = v.w;
    }
    #pragma unroll
    for (int p = 0; p < 8; ++p) {
        const int idx = p * 256 + t;        // 0..2047
        const int kr = idx >> 5;            // 0..63
        const int c4 = (idx & 31) * 4;
        *reinterpret_cast<float4*>(&Wl[kr][c4]) =
            *reinterpret_cast<const float4*>(W + (size_t)(k0 + kr) * H_ + c4);
    }
    __syncthreads();

    const int cg = t & 15;   // cols 8*cg..
    const int rg = t >> 4;   // rows 4*rg..
    float acc[4][8] = {};

    #pragma unroll 8
    for (int k = 0; k < 64; ++k) {
        const float4 av = *reinterpret_cast<const float4*>(&At[k][rg * 4]);
        const float4 b0 = *reinterpret_cast<const float4*>(&Wl[k][cg * 8]);
        const float4 b1 = *reinterpret_cast<const float4*>(&Wl[k][cg * 8 + 4]);
        const float aa[4] = {av.x, av.y, av.z, av.w};
        const float bb[8] = {b0.x, b0.y, b0.z, b0.w, b1.x, b1.y, b1.z, b1.w};
        #pragma unroll
        for (int r = 0; r < 4; ++r)
            #pragma unroll
            for (int c = 0; c < 8; ++c)
                acc[r][c] = fmaf(aa[r], bb[c], acc[r][c]);
    }

    float* __restrict__ dst = Pp + (size_t)ks * (4096 * 128);
    #pragma unroll
    for (int r = 0; r < 4; ++r) {
        const int grow = xb * 64 + rg * 4 + r;
        *reinterpret_cast<float4*>(dst + (size_t)grow * H_ + cg * 8) =
            make_float4(acc[r][0], acc[r][1], acc[r][2], acc[r][3]);
        *reinterpret_cast<float4*>(dst + (size_t)grow * H_ + cg * 8 + 4) =
            make_float4(acc[r][4], acc[r][5], acc[r][6], acc[r][7]);
    }
}

// ---------------------------------------------------------------------------
// proj_add: QKp = C2 * sum_s Pp[s]; also builds the wp pair table.
// ---------------------------------------------------------------------------
__global__ __launch_bounds__(256) void proj_add_kernel(
    const float* __restrict__ Pp, const float* __restrict__ wv,
    float* __restrict__ QKp, float* __restrict__ wp)
{
    const int i = blockIdx.x * 256 + threadIdx.x;   // f4 index < 131072
    const float C2 = 2.88539008177792681472f;       // 2*log2(e)
    float4 s = make_float4(0.f, 0.f, 0.f, 0.f);
    #pragma unroll
    for (int p = 0; p < 8; ++p) {
        const float4 v = reinterpret_cast<const float4*>(Pp)[(size_t)p * 131072 + i];
        s.x += v.x; s.y += v.y; s.z += v.z; s.w += v.w;
    }
    s.x *= C2; s.y *= C2; s.z *= C2; s.w *= C2;
    reinterpret_cast<float4*>(QKp)[i] = s;

    if (blockIdx.x == 0 && threadIdx.x < 64) {
        const float2 w2 = reinterpret_cast<const float2*>(wv)[threadIdx.x];
        const float wn0 = -2.0f * w2.x;
        const float wn1 = -2.0f * w2.y;
        reinterpret_cast<float4*>(wp)[threadIdx.x] =
            make_float4(wn0, wn1, wn0 + wn1, 0.0f);
    }
}

// ---------------------------------------------------------------------------
// score: raw scores. Block = 8 q x 256 k, 256 thr; wave w owns q rows
// (q0+2w, q0+2w+1), lane = k. Q and wp via wave-uniform (scalar) loads;
// K staged in LDS (conflict-free [64][33] float4). grid (64, 2, 4).
//   score'[q,k] = sum_h wn_h / (1 + exp2(qs_h + ks_h))   (inputs pre-scaled)
// pairwise rcp fusion: 4 exp2 + 2 rcp per 4 h.
// ---------------------------------------------------------------------------
__global__ __launch_bounds__(256) void score_kernel(
    const float* __restrict__ QKp, const float* __restrict__ wp,
    float* __restrict__ Sc)
{
    const int b    = blockIdx.z;
    const int ky   = blockIdx.y;              // 0..1
    const int q0   = blockIdx.x * 8;
    const int t    = threadIdx.x;
    const int lane = t & 63;
    const int wvid = __builtin_amdgcn_readfirstlane(t >> 6);

    __shared__ __align__(16) float4 Ks[64][33];

    const float* __restrict__ Kpb = QKp + (size_t)(2048 + b * NK_) * H_;
    const float4* __restrict__ QA =
        reinterpret_cast<const float4*>(QKp + (size_t)(b * NQ_ + q0 + 2 * wvid) * H_);
    const float4* __restrict__ QB = QA + (H_ / 4);
    const float4* __restrict__ wp4 = reinterpret_cast<const float4*>(wp);

    const int kbase = ky * 256;
    float* __restrict__ outA = Sc + ((size_t)b * NQ_ + q0 + 2 * wvid) * NK_ + kbase;
    float* __restrict__ outB = outA + NK_;

    for (int kc = 0; kc < 4; ++kc) {
        if (kc) __syncthreads();
        #pragma unroll
        for (int p = 0; p < 8; ++p) {
            const int idx = p * 256 + t;      // 0..2047
            const int kr  = idx >> 5;
            const int h4  = idx & 31;
            Ks[kr][h4] = *reinterpret_cast<const float4*>(
                Kpb + (size_t)(kbase + kc * 64 + kr) * H_ + h4 * 4);
        }
        __syncthreads();

        float sA = 0.0f, sB = 0.0f;
        #pragma unroll 8
        for (int g = 0; g < 32; ++g) {
            const float4 kv = Ks[lane][g];
            const float4 qa = QA[g];
            const float4 qb = QB[g];
            const float4 wa = wp4[2 * g];
            const float4 wb = wp4[2 * g + 1];
            {
                const float e0 = fexp2(qa.x + kv.x);
                const float e1 = fexp2(qa.y + kv.y);
                const float e2 = fexp2(qa.z + kv.z);
                const float e3 = fexp2(qa.w + kv.w);
                float n0 = fmaf(wa.x, e1, wa.z); n0 = fmaf(wa.y, e0, n0);
                float n1 = fmaf(wb.x, e3, wb.z); n1 = fmaf(wb.y, e2, n1);
                const float d0 = (1.0f + e0) * (1.0f + e1);
                const float d1 = (1.0f + e2) * (1.0f + e3);
                sA = fmaf(n0, frcp(d0), sA);
                sA = fmaf(n1, frcp(d1), sA);
            }
            {
                const float e0 = fexp2(qb.x + kv.x);
                const float e1 = fexp2(qb.y + kv.y);
                const float e2 = fexp2(qb.z + kv.z);
                const float e3 = fexp2(qb.w + kv.w);
                float n0 = fmaf(wa.x, e1, wa.z); n0 = fmaf(wa.y, e0, n0);
                float n1 = fmaf(wb.x, e3, wb.z); n1 = fmaf(wb.y, e2, n1);
                const float d0 = (1.0f + e0) * (1.0f + e1);
                const float d1 = (1.0f + e2) * (1.0f + e3);
                sB = fmaf(n0, frcp(d0), sB);
                sB = fmaf(n1, frcp(d1), sB);
            }
        }
        outA[kc * 64 + lane] = sA;
        outB[kc * 64 + lane] = sB;
    }
}

// ---------------------------------------------------------------------------
// softmax: one wave per row, in place on Sc, mask k >= valid_lens[b].
// grid 512 x 256 thr (4 rows/block).
// ---------------------------------------------------------------------------
__global__ __launch_bounds__(256) void softmax_kernel(
    float* __restrict__ Sc, const int* __restrict__ valid_lens)
{
    const int row  = blockIdx.x * 4 + (threadIdx.x >> 6);   // 0..2047
    const int lane = threadIdx.x & 63;
    const int b    = row >> 9;
    const int vl   = valid_lens[b];
    float* __restrict__ p = Sc + (size_t)row * NK_;

    const int k0 = lane * 8;
    float4 v0 = reinterpret_cast<const float4*>(p)[lane * 2];
    float4 v1 = reinterpret_cast<const float4*>(p)[lane * 2 + 1];
    float v[8] = {v0.x, v0.y, v0.z, v0.w, v1.x, v1.y, v1.z, v1.w};

    float m = -1e30f;
    #pragma unroll
    for (int j = 0; j < 8; ++j) {
        v[j] = (k0 + j < vl) ? v[j] : -1e30f;
        m = fmaxf(m, v[j]);
    }
    #pragma unroll
    for (int off = 32; off >= 1; off >>= 1)
        m = fmaxf(m, __shfl_xor(m, off, 64));

    const float L2E = 1.44269504088896340736f;
    float e[8];
    float sum = 0.0f;
    #pragma unroll
    for (int j = 0; j < 8; ++j) {
        e[j] = fexp2((v[j] - m) * L2E);
        sum += e[j];
    }
    #pragma unroll
    for (int off = 32; off >= 1; off >>= 1)
        sum += __shfl_xor(sum, off, 64);

    const float inv = frcp(sum);
    reinterpret_cast<float4*>(p)[lane * 2] =
        make_float4(e[0] * inv, e[1] * inv, e[2] * inv, e[3] * inv);
    reinterpret_cast<float4*>(p)[lane * 2 + 1] =
        make_float4(e[4] * inv, e[5] * inv, e[6] * inv, e[7] * inv);
}

// ---------------------------------------------------------------------------
// av_gemm: partial W@V. Block: 128x128 tile, 8x8 thread tile, single 64-k
// chunk (k-split 8). grid (4, 4, 32): z = b*8 + ks.
// ---------------------------------------------------------------------------
__global__ __launch_bounds__(256) void av_gemm_kernel(
    const float* __restrict__ Sc, const float* __restrict__ V,
    float* __restrict__ Pg)
{
    const int c0 = blockIdx.x * 128;
    const int r0 = blockIdx.y * 128;
    const int z  = blockIdx.z;
    const int b  = z >> 3;
    const int ks = z & 7;
    const int k0 = ks * 64;
    const int t  = threadIdx.x;

    __shared__ float At[64][132];   // [k][q-row]
    __shared__ float Bl[64][132];   // [k][col]

    #pragma unroll
    for (int p = 0; p < 8; ++p) {
        const int idx = p * 256 + t;      // 0..2047
        const int row = idx >> 4;         // 0..127
        const int kq  = (idx & 15) * 4;
        const float4 v = *reinterpret_cast<const float4*>(
            Sc + ((size_t)b * NQ_ + r0 + row) * NK_ + k0 + kq);
        At[kq + 0][row] = v.x; At[kq + 1][row] = v.y;
        At[kq + 2][row] = v.z; At[kq + 3][row] = v.w;
    }
    #pragma unroll
    for (int p = 0; p < 8; ++p) {
        const int idx = p * 256 + t;
        const int kr = idx >> 5;          // 0..63
        const int c4 = (idx & 31) * 4;
        *reinterpret_cast<float4*>(&Bl[kr][c4]) =
            *reinterpret_cast<const float4*>(
                V + ((size_t)b * NK_ + k0 + kr) * D_ + c0 + c4);
    }
    __syncthreads();

    const int cg = t & 15;   // cols 8*cg..
    const int rg = t >> 4;   // rows 8*rg..
    float acc[8][8] = {};

    #pragma unroll 4
    for (int k = 0; k < 64; ++k) {
        const float4 a0 = *reinterpret_cast<const float4*>(&At[k][rg * 8]);
        const float4 a1 = *reinterpret_cast<const float4*>(&At[k][rg * 8 + 4]);
        const float4 b0 = *reinterpret_cast<const float4*>(&Bl[k][cg * 8]);
        const float4 b1 = *reinterpret_cast<const float4*>(&Bl[k][cg * 8 + 4]);
        const float aa[8] = {a0.x, a0.y, a0.z, a0.w, a1.x, a1.y, a1.z, a1.w};
        const float bb[8] = {b0.x, b0.y, b0.z, b0.w, b1.x, b1.y, b1.z, b1.w};
        #pragma unroll
        for (int r = 0; r < 8; ++r)
            #pragma unroll
            for (int c = 0; c < 8; ++c)
                acc[r][c] = fmaf(aa[r], bb[c], acc[r][c]);
    }

    float* __restrict__ dst = Pg + (size_t)ks * (2048 * 512);
    #pragma unroll
    for (int r = 0; r < 8; ++r) {
        const size_t ro = ((size_t)b * NQ_ + r0 + rg * 8 + r) * D_ + c0 + cg * 8;
        *reinterpret_cast<float4*>(dst + ro) =
            make_float4(acc[r][0], acc[r][1], acc[r][2], acc[r][3]);
        *reinterpret_cast<float4*>(dst + ro + 4) =
            make_float4(acc[r][4], acc[r][5], acc[r][6], acc[r][7]);
    }
}

// ---------------------------------------------------------------------------
// gemm_add: out = sum_s Pg[s]
// ---------------------------------------------------------------------------
__global__ __launch_bounds__(256) void gemm_add_kernel(
    const float4* __restrict__ Pg, float4* __restrict__ out)
{
    const int i = blockIdx.x * 256 + threadIdx.x;   // < 262144
    float4 s = make_float4(0.f, 0.f, 0.f, 0.f);
    #pragma unroll
    for (int p = 0; p < 8; ++p) {
        const float4 v = Pg[(size_t)p * 262144 + i];
        s.x += v.x; s.y += v.y; s.z += v.z; s.w += v.w;
    }
    out[i] = s;
}

extern "C" void kernel_launch(void* const* d_in, const int* in_sizes, int n_in,
                              void* d_out, int out_size, void* d_ws, size_t ws_size,
                              hipStream_t stream) {
    (void)in_sizes; (void)n_in; (void)out_size; (void)ws_size;

    const float* Q   = (const float*)d_in[0];
    const float* K   = (const float*)d_in[1];
    const float* V   = (const float*)d_in[2];
    const float* Wq  = (const float*)d_in[3];
    const float* Wk  = (const float*)d_in[4];
    const float* wv  = (const float*)d_in[5];
    const int*   vl  = (const int*)d_in[6];
    float* out = (float*)d_out;

    float* ws  = (float*)d_ws;
    float* QKp = ws + WS_QKP;
    float* Pp  = ws + WS_PP;
    float* wp  = ws + WS_WP;
    float* Sc  = ws + WS_SC;
    float* Pg  = ws + WS_PG;

    proj_kernel<<<dim3(64, 8), 256, 0, stream>>>(Q, K, Wq, Wk, Pp);
    proj_add_kernel<<<dim3(512), 256, 0, stream>>>(Pp, wv, QKp, wp);
    score_kernel<<<dim3(64, 2, 4), 256, 0, stream>>>(QKp, wp, Sc);
    softmax_kernel<<<dim3(512), 256, 0, stream>>>(Sc, vl);
    av_gemm_kernel<<<dim3(4, 4, 32), 256, 0, stream>>>(Sc, V, Pg);
    gemm_add_kernel<<<dim3(1024), 256, 0, stream>>>((const float4*)Pg, (float4*)out);
}

// Round 4
// 131.394 us; speedup vs baseline: 3.0954x; 1.1035x over previous
//
#include <hip/hip_runtime.h>

#define B_   4
#define NQ_  512
#define NK_  512
#define D_   512
#define H_   128

typedef __attribute__((ext_vector_type(8))) short short8;
typedef __attribute__((ext_vector_type(4))) float f32x4;

__device__ __forceinline__ float fexp2(float x) { return __builtin_amdgcn_exp2f(x); }
__device__ __forceinline__ float frcp(float x)  { return __builtin_amdgcn_rcpf(x); }
__device__ __forceinline__ unsigned short f2bf(float f) {
    unsigned int u = __builtin_bit_cast(unsigned int, f);
    u += 0x7FFFu + ((u >> 16) & 1u);          // RNE
    return (unsigned short)(u >> 16);
}

// ws layout (float offsets)
#define WS_QKP   0          // [4096][128] fp32: Qp rows 0..2047, Kp 2048..4095 (pre-scaled 2*log2e)
#define WS_PP    524288     // [8][4096][128] fp32 proj partials
#define WS_WP    4718592    // [64] float4 pair table
#define WS_WBF   4718848    // ushort region: [4][512][512] bf16 softmax weights (524288 floats)
#define WS_VT    5243136    // ushort region: [4][512][512] bf16 V^T (d-major)   (524288 floats)

// ---------------------------------------------------------------------------
// proj: partial X@W. xb 0..15 = Q@Wq rows, 16..31 = K@Wk. k-split 8 (ks=by).
// Block: 128 rows x 128 cols, 256 thr, 8x8 thread tile, k staged in 32-chunks.
// ---------------------------------------------------------------------------
__global__ __launch_bounds__(256) void proj_kernel(
    const float* __restrict__ Q, const float* __restrict__ K,
    const float* __restrict__ Wq, const float* __restrict__ Wk,
    float* __restrict__ Pp)
{
    const int xb = blockIdx.x;            // 0..31
    const int ks = blockIdx.y;            // 0..7
    const bool isQ = xb < 16;
    const float* __restrict__ X = isQ ? Q : K;
    const float* __restrict__ W = isQ ? Wq : Wk;
    const int r0 = (xb & 15) * 128;
    const int k0 = ks * 64;
    const int t  = threadIdx.x;

    __shared__ float At[32][132];   // [k][row], transposed
    __shared__ float Wl[32][132];   // [k][col]

    const int cg = t & 15;   // cols {4cg..4cg+3} and {64+4cg..}
    const int rg = t >> 4;   // rows 8*rg..8*rg+7
    float acc[8][8] = {};

    for (int kc = 0; kc < 2; ++kc) {
        if (kc) __syncthreads();
        // X tile: 128 rows x 32 k -> At[k][row]. row = idx&127 (conflict-free
        // LDS writes; 16B/lane global pattern is L1-absorbed, lines fully used).
        #pragma unroll
        for (int p = 0; p < 4; ++p) {
            const int idx = p * 256 + t;          // 0..1023
            const int row = idx & 127;
            const int kq  = (idx >> 7) * 4;       // 0,4,..,28
            const float4 v = *reinterpret_cast<const float4*>(
                X + (size_t)(r0 + row) * D_ + k0 + kc * 32 + kq);
            At[kq + 0][row] = v.x; At[kq + 1][row] = v.y;
            At[kq + 2][row] = v.z; At[kq + 3][row] = v.w;
        }
        // W tile: 32 k x 128 cols, natural
        #pragma unroll
        for (int p = 0; p < 4; ++p) {
            const int idx = p * 256 + t;          // 0..1023
            const int kr  = idx >> 5;             // 0..31
            const int c4  = (idx & 31) * 4;
            *reinterpret_cast<float4*>(&Wl[kr][c4]) =
                *reinterpret_cast<const float4*>(
                    W + (size_t)(k0 + kc * 32 + kr) * H_ + c4);
        }
        __syncthreads();

        #pragma unroll 4
        for (int k = 0; k < 32; ++k) {
            const float4 a0 = *reinterpret_cast<const float4*>(&At[k][rg * 8]);
            const float4 a1 = *reinterpret_cast<const float4*>(&At[k][rg * 8 + 4]);
            const float4 b0 = *reinterpret_cast<const float4*>(&Wl[k][cg * 4]);
            const float4 b1 = *reinterpret_cast<const float4*>(&Wl[k][64 + cg * 4]);
            const float aa[8] = {a0.x, a0.y, a0.z, a0.w, a1.x, a1.y, a1.z, a1.w};
            const float bb[8] = {b0.x, b0.y, b0.z, b0.w, b1.x, b1.y, b1.z, b1.w};
            #pragma unroll
            for (int r = 0; r < 8; ++r)
                #pragma unroll
                for (int c = 0; c < 8; ++c)
                    acc[r][c] = fmaf(aa[r], bb[c], acc[r][c]);
        }
    }

    float* __restrict__ dst = Pp + (size_t)ks * (4096 * 128);
    #pragma unroll
    for (int r = 0; r < 8; ++r) {
        const int grow = xb * 128 + rg * 8 + r;
        *reinterpret_cast<float4*>(dst + (size_t)grow * H_ + cg * 4) =
            make_float4(acc[r][0], acc[r][1], acc[r][2], acc[r][3]);
        *reinterpret_cast<float4*>(dst + (size_t)grow * H_ + 64 + cg * 4) =
            make_float4(acc[r][4], acc[r][5], acc[r][6], acc[r][7]);
    }
}

// ---------------------------------------------------------------------------
// proj_add: QKp = C2 * sum_s Pp[s]; builds wp pair table.
// ---------------------------------------------------------------------------
__global__ __launch_bounds__(256) void proj_add_kernel(
    const float* __restrict__ Pp, const float* __restrict__ wv,
    float* __restrict__ QKp, float* __restrict__ wp)
{
    const int i = blockIdx.x * 256 + threadIdx.x;   // f4 index < 131072
    const float C2 = 2.88539008177792681472f;       // 2*log2(e)
    float4 s = make_float4(0.f, 0.f, 0.f, 0.f);
    #pragma unroll
    for (int p = 0; p < 8; ++p) {
        const float4 v = reinterpret_cast<const float4*>(Pp)[(size_t)p * 131072 + i];
        s.x += v.x; s.y += v.y; s.z += v.z; s.w += v.w;
    }
    s.x *= C2; s.y *= C2; s.z *= C2; s.w *= C2;
    reinterpret_cast<float4*>(QKp)[i] = s;

    if (blockIdx.x == 0 && threadIdx.x < 64) {
        const float2 w2 = reinterpret_cast<const float2*>(wv)[threadIdx.x];
        const float wn0 = -2.0f * w2.x;
        const float wn1 = -2.0f * w2.y;
        reinterpret_cast<float4*>(wp)[threadIdx.x] =
            make_float4(wn0, wn1, wn0 + wn1, 0.0f);
    }
}

// ---------------------------------------------------------------------------
// transposeV: V (k-major fp32) -> Vt (d-major bf16), 64x64 tiles via LDS.
// ---------------------------------------------------------------------------
__global__ __launch_bounds__(256) void transposeV_kernel(
    const float* __restrict__ V, unsigned short* __restrict__ Vt)
{
    const int kt = blockIdx.x, dt = blockIdx.y, b = blockIdx.z;
    const int t  = threadIdx.x;
    __shared__ float Vl[64][69];

    #pragma unroll
    for (int p = 0; p < 4; ++p) {
        const int idx = p * 256 + t;
        const int r  = idx >> 4;             // k-row 0..63
        const int c4 = (idx & 15) * 4;       // d-col group
        const float4 v = *reinterpret_cast<const float4*>(
            V + ((size_t)b * NK_ + kt * 64 + r) * D_ + dt * 64 + c4);
        Vl[r][c4 + 0] = v.x; Vl[r][c4 + 1] = v.y;
        Vl[r][c4 + 2] = v.z; Vl[r][c4 + 3] = v.w;
    }
    __syncthreads();

    #pragma unroll
    for (int p = 0; p < 4; ++p) {
        const int idx = p * 256 + t;
        const int d  = idx >> 4;             // d-row 0..63
        const int k4 = (idx & 15) * 4;       // k group
        ushort4 o;
        o.x = f2bf(Vl[k4 + 0][d]); o.y = f2bf(Vl[k4 + 1][d]);
        o.z = f2bf(Vl[k4 + 2][d]); o.w = f2bf(Vl[k4 + 3][d]);
        *reinterpret_cast<ushort4*>(
            Vt + ((size_t)b * D_ + dt * 64 + d) * NK_ + kt * 64 + k4) = o;
    }
}

// ---------------------------------------------------------------------------
// score+softmax fused: block = 8 q-rows x all 512 k, 512 thr (wave w -> row
// q0+w). K staged 64 rows/chunk in LDS; Q row + wp via wave-uniform scalar
// loads. Scores live in registers (vals[8] = softmax lane layout). Writes
// bf16 weights.
// ---------------------------------------------------------------------------
__global__ __launch_bounds__(512) void score_softmax_kernel(
    const float* __restrict__ QKp, const float* __restrict__ wp,
    const int* __restrict__ valid_lens, unsigned short* __restrict__ Wbf)
{
    const int b  = blockIdx.y;
    const int q0 = blockIdx.x * 8;
    const int t  = threadIdx.x;
    const int w    = __builtin_amdgcn_readfirstlane(t >> 6);   // 0..7
    const int lane = t & 63;

    __shared__ __align__(16) float4 Ks[64][33];

    const float4* __restrict__ Q4 =
        reinterpret_cast<const float4*>(QKp + (size_t)(b * NQ_ + q0 + w) * H_);
    const float4* __restrict__ wp4 = reinterpret_cast<const float4*>(wp);
    const float4* __restrict__ Kp4 =
        reinterpret_cast<const float4*>(QKp + (size_t)(2048 + b * NK_) * H_);

    float vals[8];

    for (int c = 0; c < 8; ++c) {
        if (c) __syncthreads();
        #pragma unroll
        for (int p = 0; p < 4; ++p) {
            const int idx = p * 512 + t;       // 0..2047
            const int r   = idx >> 5;          // 0..63
            const int h4  = idx & 31;
            Ks[r][h4] = Kp4[(size_t)(c * 64 + r) * 32 + h4];
        }
        __syncthreads();

        float s = 0.0f;
        #pragma unroll 8
        for (int g = 0; g < 32; ++g) {
            const float4 kv = Ks[lane][g];
            const float4 qa = Q4[g];
            const float4 wa = wp4[2 * g];
            const float4 wb = wp4[2 * g + 1];
            const float e0 = fexp2(qa.x + kv.x);
            const float e1 = fexp2(qa.y + kv.y);
            const float e2 = fexp2(qa.z + kv.z);
            const float e3 = fexp2(qa.w + kv.w);
            float n0 = fmaf(wa.x, e1, wa.z); n0 = fmaf(wa.y, e0, n0);
            float n1 = fmaf(wb.x, e3, wb.z); n1 = fmaf(wb.y, e2, n1);
            const float d0 = (1.0f + e0) * (1.0f + e1);
            const float d1 = (1.0f + e2) * (1.0f + e3);
            s = fmaf(n0, frcp(d0), s);
            s = fmaf(n1, frcp(d1), s);
        }
        vals[c] = s;
    }

    // in-register masked softmax over the wave's row
    const int vl = valid_lens[b];
    float m = -1e30f;
    #pragma unroll
    for (int c = 0; c < 8; ++c) {
        const int k = c * 64 + lane;
        vals[c] = (k < vl) ? vals[c] : -1e30f;
        m = fmaxf(m, vals[c]);
    }
    #pragma unroll
    for (int off = 32; off >= 1; off >>= 1)
        m = fmaxf(m, __shfl_xor(m, off, 64));

    const float L2E = 1.44269504088896340736f;
    float e[8];
    float sum = 0.0f;
    #pragma unroll
    for (int c = 0; c < 8; ++c) {
        e[c] = fexp2((vals[c] - m) * L2E);
        sum += e[c];
    }
    #pragma unroll
    for (int off = 32; off >= 1; off >>= 1)
        sum += __shfl_xor(sum, off, 64);

    const float inv = frcp(sum);
    unsigned short* __restrict__ dst = Wbf + (size_t)(b * NQ_ + q0 + w) * NK_;
    #pragma unroll
    for (int c = 0; c < 8; ++c)
        dst[c * 64 + lane] = f2bf(e[c] * inv);
}

// ---------------------------------------------------------------------------
// av_gemm (bf16 MFMA 16x16x32): O[b] = W@V. Block 64q x 64d, 4 waves; wave w
// owns rows w*16..+15, all 64 cols (4 col-tiles). K in 128-chunks via LDS.
// A (weights) and Bt (=V^T) both k-contiguous -> ds_read_b128 frags.
// Layouts per verified notes: A[m=lane&15][k=quad*8+j]; B[k][n=lane&15];
// C/D col=lane&15, row=quad*4+reg.
// ---------------------------------------------------------------------------
__global__ __launch_bounds__(256) void av_gemm_kernel(
    const unsigned short* __restrict__ Wbf, const unsigned short* __restrict__ Vt,
    float* __restrict__ O)
{
    const int c0 = blockIdx.x * 64;
    const int r0 = blockIdx.y * 64;
    const int b  = blockIdx.z;
    const int t  = threadIdx.x;
    const int wave = __builtin_amdgcn_readfirstlane(t >> 6);
    const int lane = t & 63;
    const int m    = lane & 15;
    const int quad = lane >> 4;

    __shared__ unsigned short Al [64][136];   // [q][k], 272B row stride (16B mult)
    __shared__ unsigned short Btl[64][136];   // [d][k]

    f32x4 acc0 = {0.f,0.f,0.f,0.f}, acc1 = {0.f,0.f,0.f,0.f};
    f32x4 acc2 = {0.f,0.f,0.f,0.f}, acc3 = {0.f,0.f,0.f,0.f};

    for (int kc = 0; kc < 4; ++kc) {
        if (kc) __syncthreads();
        #pragma unroll
        for (int p = 0; p < 4; ++p) {
            const int idx = p * 256 + t;          // 0..1023
            const int rl = idx >> 4;              // 0..63
            const int k8 = (idx & 15) * 8;
            *reinterpret_cast<uint4*>(&Al[rl][k8]) =
                *reinterpret_cast<const uint4*>(
                    Wbf + ((size_t)b * NQ_ + r0 + rl) * NK_ + kc * 128 + k8);
            *reinterpret_cast<uint4*>(&Btl[rl][k8]) =
                *reinterpret_cast<const uint4*>(
                    Vt + ((size_t)b * D_ + c0 + rl) * NK_ + kc * 128 + k8);
        }
        __syncthreads();

        #pragma unroll
        for (int sub = 0; sub < 4; ++sub) {
            const int kcol = sub * 32 + quad * 8;
            const short8 a = *reinterpret_cast<const short8*>(&Al[wave * 16 + m][kcol]);
            const short8 b0 = *reinterpret_cast<const short8*>(&Btl[ 0 + m][kcol]);
            const short8 b1 = *reinterpret_cast<const short8*>(&Btl[16 + m][kcol]);
            const short8 b2 = *reinterpret_cast<const short8*>(&Btl[32 + m][kcol]);
            const short8 b3 = *reinterpret_cast<const short8*>(&Btl[48 + m][kcol]);
            acc0 = __builtin_amdgcn_mfma_f32_16x16x32_bf16(a, b0, acc0, 0, 0, 0);
            acc1 = __builtin_amdgcn_mfma_f32_16x16x32_bf16(a, b1, acc1, 0, 0, 0);
            acc2 = __builtin_amdgcn_mfma_f32_16x16x32_bf16(a, b2, acc2, 0, 0, 0);
            acc3 = __builtin_amdgcn_mfma_f32_16x16x32_bf16(a, b3, acc3, 0, 0, 0);
        }
    }

    const size_t rowbase = (size_t)b * NQ_ + r0 + wave * 16 + quad * 4;
    #pragma unroll
    for (int i = 0; i < 4; ++i) {
        float* __restrict__ orow = O + (rowbase + i) * D_ + c0 + m;
        orow[ 0] = acc0[i];
        orow[16] = acc1[i];
        orow[32] = acc2[i];
        orow[48] = acc3[i];
    }
}

extern "C" void kernel_launch(void* const* d_in, const int* in_sizes, int n_in,
                              void* d_out, int out_size, void* d_ws, size_t ws_size,
                              hipStream_t stream) {
    (void)in_sizes; (void)n_in; (void)out_size; (void)ws_size;

    const float* Q   = (const float*)d_in[0];
    const float* K   = (const float*)d_in[1];
    const float* V   = (const float*)d_in[2];
    const float* Wq  = (const float*)d_in[3];
    const float* Wk  = (const float*)d_in[4];
    const float* wv  = (const float*)d_in[5];
    const int*   vl  = (const int*)d_in[6];
    float* out = (float*)d_out;

    float* ws  = (float*)d_ws;
    float* QKp = ws + WS_QKP;
    float* Pp  = ws + WS_PP;
    float* wp  = ws + WS_WP;
    unsigned short* Wbf = (unsigned short*)(ws + WS_WBF);
    unsigned short* Vt  = (unsigned short*)(ws + WS_VT);

    proj_kernel<<<dim3(32, 8), 256, 0, stream>>>(Q, K, Wq, Wk, Pp);
    proj_add_kernel<<<dim3(512), 256, 0, stream>>>(Pp, wv, QKp, wp);
    transposeV_kernel<<<dim3(8, 8, 4), 256, 0, stream>>>(V, Vt);
    score_softmax_kernel<<<dim3(64, 4), 512, 0, stream>>>(QKp, wp, vl, Wbf);
    av_gemm_kernel<<<dim3(8, 8, 4), 256, 0, stream>>>(Wbf, Vt, out);
}